// Round 3
// baseline (251.259 us; speedup 1.0000x reference)
//
#include <hip/hip_runtime.h>
#include <hip/hip_bf16.h>

typedef unsigned short ushortx8 __attribute__((ext_vector_type(8)));

__device__ __forceinline__ float lrelu(float x) { return x >= 0.f ? x : 0.01f * x; }
__device__ __forceinline__ float bf2f(unsigned short b) {
  return __uint_as_float(((unsigned int)b) << 16);
}

// Kernel 1: per-node u = x@W1 + b_in, v = x@W2, stored bf16.
// One wave per node; lane d holds W1[:,d], W2[:,d] in registers (128 VGPR).
__global__ __launch_bounds__(256) void k1_uv(
    const float* __restrict__ x, const float* __restrict__ W_in,
    const float* __restrict__ b_in,
    __hip_bfloat16* __restrict__ u, __hip_bfloat16* __restrict__ v, int N) {
  const int lane = threadIdx.x & 63;
  float w1[64], w2[64];
#pragma unroll
  for (int k = 0; k < 64; ++k) w1[k] = W_in[k * 64 + lane];
#pragma unroll
  for (int k = 0; k < 64; ++k) w2[k] = W_in[4096 + k * 64 + lane];
  const float bi = b_in[lane];
  const int wid = (int)((blockIdx.x * blockDim.x + threadIdx.x) >> 6);
  const int nw  = (int)((gridDim.x * blockDim.x) >> 6);
  for (int n0 = wid; n0 < N; n0 += nw) {
    const int n = __builtin_amdgcn_readfirstlane(n0);  // uniform -> scalar loads
    const float4* xr = (const float4*)(x + (size_t)n * 64);
    float ua = bi, va = 0.f;
#pragma unroll
    for (int q = 0; q < 16; ++q) {
      const float4 xv = xr[q];
      ua = fmaf(xv.x, w1[4*q+0], ua); va = fmaf(xv.x, w2[4*q+0], va);
      ua = fmaf(xv.y, w1[4*q+1], ua); va = fmaf(xv.y, w2[4*q+1], va);
      ua = fmaf(xv.z, w1[4*q+2], ua); va = fmaf(xv.z, w2[4*q+2], va);
      ua = fmaf(xv.w, w1[4*q+3], ua); va = fmaf(xv.w, w2[4*q+3], va);
    }
    u[(size_t)n * 64 + lane] = __float2bfloat16(ua);
    v[(size_t)n * 64 + lane] = __float2bfloat16(va);
  }
}

// Kernel 2: per-edge scalar logit e = sum_d lrelu(u[src]+v[tgt])*a_w + a_b,
// then S[tgt] += exp(e). 8 lanes per edge, 16B bf16 gathers per lane.
__global__ __launch_bounds__(256) void k2_edge(
    const __hip_bfloat16* __restrict__ u, const __hip_bfloat16* __restrict__ v,
    const int* __restrict__ src, const int* __restrict__ tgt,
    const float* __restrict__ a_w, const float* __restrict__ a_b,
    float* __restrict__ S, int E) {
  const int sub = threadIdx.x & 7;
  float aw[8];
#pragma unroll
  for (int j = 0; j < 8; ++j) aw[j] = a_w[sub * 8 + j];
  const float ab = a_b[0];
  const int g0 = (int)((blockIdx.x * blockDim.x + threadIdx.x) >> 3);
  const int gs = (int)((gridDim.x * blockDim.x) >> 3);
  for (int e = g0; e < E; e += gs) {
    const int s = src[e];
    const int t = tgt[e];
    const ushortx8 ub = *(const ushortx8*)((const unsigned short*)u + (size_t)s * 64 + sub * 8);
    const ushortx8 vb = *(const ushortx8*)((const unsigned short*)v + (size_t)t * 64 + sub * 8);
    float acc = 0.f;
#pragma unroll
    for (int j = 0; j < 8; ++j) {
      const float wh = bf2f(ub[j]) + bf2f(vb[j]);
      acc = fmaf(lrelu(wh), aw[j], acc);
    }
    acc += __shfl_xor(acc, 1);
    acc += __shfl_xor(acc, 2);
    acc += __shfl_xor(acc, 4);
    if (sub == 0) atomicAdd(S + t, __expf(acc + ab));
  }
}

// Kernel 3: out[n,:] = lrelu( (x[n]@W_out + b_out) * S_n/(S_n+eps) ).
__global__ __launch_bounds__(256) void k3_out(
    const float* __restrict__ x, const float* __restrict__ W_out,
    const float* __restrict__ b_out, const float* __restrict__ S,
    float* __restrict__ out, int N) {
  const int lane = threadIdx.x & 63;
  float wo[64];
#pragma unroll
  for (int k = 0; k < 64; ++k) wo[k] = W_out[k * 64 + lane];
  const float bo = b_out[lane];
  const int wid = (int)((blockIdx.x * blockDim.x + threadIdx.x) >> 6);
  const int nw  = (int)((gridDim.x * blockDim.x) >> 6);
  for (int n0 = wid; n0 < N; n0 += nw) {
    const int n = __builtin_amdgcn_readfirstlane(n0);
    const float4* xr = (const float4*)(x + (size_t)n * 64);
    float acc = bo;
#pragma unroll
    for (int q = 0; q < 16; ++q) {
      const float4 xv = xr[q];
      acc = fmaf(xv.x, wo[4*q+0], acc);
      acc = fmaf(xv.y, wo[4*q+1], acc);
      acc = fmaf(xv.z, wo[4*q+2], acc);
      acc = fmaf(xv.w, wo[4*q+3], acc);
    }
    const float Sn = S[n];
    const float r = Sn / (Sn + 1e-6f);
    const float o = acc * r;
    out[(size_t)n * 64 + lane] = lrelu(o);
  }
}

extern "C" void kernel_launch(void* const* d_in, const int* in_sizes, int n_in,
                              void* d_out, int out_size, void* d_ws, size_t ws_size,
                              hipStream_t stream) {
  const float* x     = (const float*)d_in[0];
  const int*   src   = (const int*)d_in[1];
  const int*   tgt   = (const int*)d_in[2];
  const float* W_in  = (const float*)d_in[3];
  const float* b_in  = (const float*)d_in[4];
  const float* a_w   = (const float*)d_in[5];
  const float* a_b   = (const float*)d_in[6];
  const float* W_out = (const float*)d_in[7];
  const float* b_out = (const float*)d_in[8];
  float* out = (float*)d_out;

  const int N = in_sizes[0] / 64;
  const int E = in_sizes[1];

  // Workspace: u[N*64] bf16, v[N*64] bf16, S[N] f32  (~26 MB total)
  char* ws = (char*)d_ws;
  __hip_bfloat16* u = (__hip_bfloat16*)ws;
  __hip_bfloat16* v = (__hip_bfloat16*)(ws + (size_t)N * 64 * 2);
  float*          S = (float*)(ws + (size_t)N * 64 * 4);

  hipMemsetAsync(S, 0, (size_t)N * sizeof(float), stream);
  k1_uv <<<2048, 256, 0, stream>>>(x, W_in, b_in, u, v, N);
  k2_edge<<<2048, 256, 0, stream>>>(u, v, src, tgt, a_w, a_b, S, E);
  k3_out <<<2048, 256, 0, stream>>>(x, W_out, b_out, S, out, N);
}